// Round 12
// baseline (469.355 us; speedup 1.0000x reference)
//
#include <hip/hip_runtime.h>
#include <hip/hip_cooperative_groups.h>

namespace cg = cooperative_groups;

// AttentionGCN forward. B=32, N=1024, F=64, PRE=64, L1=128. Output y[32].
//
// ONE cooperative kernel (512 blocks x 256 thr, co-resident), phases split by
// grid.sync() -- eliminates 4 inter-kernel launch gaps:
//   DEG  : disq[b,n] = rsqrt(rowsum(A))            (block (b,y) owns 64 rows)
//   XT   : xtb[b,f,j] = bf16(d_j * x[b,j,f])       (block (b,y) owns 64 j's)
//   SPMM : MFMA spmm, A f32 staged via global_load_lds (pre-swizzled source,
//          linear LDS dest), cvt in-reg -> h in LDS -> values -> logits
//   TAIL : softmax (redundant per chunk-block, y<8) + 128-node pool -> vpart
//   OUT  : block(0,0): y[b] = (sum_ch vpart) . Wout + bout

#define N_ 1024
#define F_ 64

typedef short s16x8 __attribute__((ext_vector_type(8)));
typedef float f32x4 __attribute__((ext_vector_type(4)));
typedef unsigned short u16x8 __attribute__((ext_vector_type(8)));

__device__ __forceinline__ unsigned short bf16rne(float f) {
  union { float f; unsigned u; } v; v.f = f;
  unsigned r = v.u + 0x7fffu + ((v.u >> 16) & 1u);
  return (unsigned short)(r >> 16);
}

__device__ __forceinline__ void fma_row(float (&a)[4], const float4 av,
                                        const float4 x0, const float4 x1,
                                        const float4 x2, const float4 x3) {
  a[0] += av.x * x0.x + av.y * x1.x + av.z * x2.x + av.w * x3.x;
  a[1] += av.x * x0.y + av.y * x1.y + av.z * x2.y + av.w * x3.y;
  a[2] += av.x * x0.z + av.y * x1.z + av.z * x2.z + av.w * x3.z;
  a[3] += av.x * x0.w + av.y * x1.w + av.z * x2.w + av.w * x3.w;
}

// global -> LDS direct DMA, 16B per lane; LDS dest = wave-uniform base + lane*16
__device__ __forceinline__ void stage16(const void* g, void* l) {
  auto gp = reinterpret_cast<const __attribute__((address_space(1))) void*>(
      reinterpret_cast<uintptr_t>(g));
  auto lp = reinterpret_cast<__attribute__((address_space(3))) void*>(
      reinterpret_cast<uintptr_t>(l));
  __builtin_amdgcn_global_load_lds(gp, lp, 16, 0, 0);
}

__global__ __launch_bounds__(256, 2) void k_mega(
    const float* __restrict__ A, const float* __restrict__ x,
    const float* __restrict__ alphap,
    const float* __restrict__ Wpre, const float* __restrict__ bpre,
    const float* __restrict__ Wfc1, const float* __restrict__ bfc1,
    const float* __restrict__ Wkeys, const float* __restrict__ bkeysp,
    const float* __restrict__ Wout, const float* __restrict__ boutp,
    float* __restrict__ disq, unsigned short* __restrict__ xtb,
    float* __restrict__ values, float* __restrict__ logits,
    float* __restrict__ vpart, float* __restrict__ y) {
  // LDS union (54272 B -> 2-3 blocks/CU):
  //  SPMM: [0,49152) staging 2x24576 (A 16K f32 | B 8K bf16); hs @0 after loop,
  //        wft @17408, part @50176
  //  XT:   xs f32[64][68] @0
  //  TAIL: sc f32[1024] @0, red @4096, pool[4][64] @4224
  __shared__ __attribute__((aligned(16))) char smem[54272];
  float (*hs)[68]   = (float(*)[68])(smem);
  float (*wft)[128] = (float(*)[128])(smem + 17408);
  float (*part)[16] = (float(*)[16])(smem + 50176);

  cg::grid_group grid = cg::this_grid();

  const int t  = threadIdx.x;
  const int b  = blockIdx.x;          // batch  [0,32)
  const int yb = blockIdx.y;          // tile   [0,16)
  const int w  = t >> 6, l = t & 63;
  const int i0 = yb * 64;

  // ================= Phase DEG =================
  {
    const float* Ab = A + ((size_t)b << 20) + (size_t)i0 * N_;
    // wave w handles rows w*16..w*16+15, 4 at a time (16 loads in flight)
#pragma unroll
    for (int rq = 0; rq < 4; ++rq) {
      float4 v[4][4];
#pragma unroll
      for (int i = 0; i < 4; ++i) {
        const float4* rp = (const float4*)(Ab + (size_t)(w * 16 + rq * 4 + i) * N_);
#pragma unroll
        for (int c = 0; c < 4; ++c) v[i][c] = rp[c * 64 + l];
      }
#pragma unroll
      for (int i = 0; i < 4; ++i) {
        float s = 0.f;
#pragma unroll
        for (int c = 0; c < 4; ++c) s += v[i][c].x + v[i][c].y + v[i][c].z + v[i][c].w;
#pragma unroll
        for (int off = 32; off > 0; off >>= 1) s += __shfl_down(s, off, 64);
        if (l == 0) {
          float d = (s != 0.f) ? s : 1.f;
          disq[(b << 10) + i0 + w * 16 + rq * 4 + i] = rsqrtf(d);
        }
      }
    }
  }
  __threadfence();
  grid.sync();

  // ================= Phase XT =================
  {
    float (*xs)[68] = (float(*)[68])(smem);
    const int j0 = i0;
    const float* xb = x + ((size_t)b << 16);
    const float* dq = disq + (b << 10);
#pragma unroll
    for (int it = 0; it < 4; ++it) {
      int idx = it * 1024 + t * 4;
      int jj = idx >> 6, ff = idx & 63;
      float4 vv = *(const float4*)&xb[(size_t)(j0 + jj) * F_ + ff];
      float sc = dq[j0 + jj];
      vv.x *= sc; vv.y *= sc; vv.z *= sc; vv.w *= sc;
      *(float4*)&xs[jj][ff] = vv;
    }
    __syncthreads();
    const int f = l, ch2 = w;   // f = t&63, chunk = t>>6
    u16x8 o0, o1;
#pragma unroll
    for (int jj = 0; jj < 8; ++jj) o0[jj] = bf16rne(xs[ch2 * 16 + jj][f]);
#pragma unroll
    for (int jj = 0; jj < 8; ++jj) o1[jj] = bf16rne(xs[ch2 * 16 + 8 + jj][f]);
    unsigned short* dst = xtb + (size_t)(b * 64 + f) * N_ + j0 + ch2 * 16;
    *(u16x8*)dst = o0;
    *(u16x8*)(dst + 8) = o1;
  }
  __threadfence();
  grid.sync();

  // ================= Phase SPMM + MLP =================
  f32x4 acc0 = {0.f, 0.f, 0.f, 0.f}, acc1 = acc0, acc2 = acc0, acc3 = acc0;
  const int lr = l & 15, kq = l >> 4;
  {
    const size_t bb = ((size_t)b << 20);
    const int half = (w & 1) * 32;
    // A waves (w<2): 8 instrs x (4 rows x 256B); pre-swizzled source slots
    const int srow4 = l >> 4;
    const int mslot = l & 15;
    const float* gA0 = A + bb + (size_t)(i0 + half + srow4) * 1024;
    int xoff[4];
#pragma unroll
    for (int q = 0; q < 4; ++q) xoff[q] = (mslot ^ ((q * 4 + srow4) & 15)) << 2;
    // B waves (w>=2): 4 instrs x (8 rows x 128B)
    const int srow8 = l >> 3;
    const int schB  = ((l & 7) ^ srow8) * 8;
    const unsigned short* gsB = xtb + (size_t)(b * 64 + half + srow8) * N_ + schB;

    auto STAGE = [&](char* bufp, int ksv) {
      if (w < 2) {
        const int ko = ksv * 64;
#pragma unroll
        for (int j = 0; j < 8; ++j)
          stage16(gA0 + (size_t)j * 4096 + xoff[j & 3] + ko,
                  bufp + (half + j * 4) * 256);
      } else {
        const int ko = ksv * 64;
#pragma unroll
        for (int j = 0; j < 4; ++j)
          stage16(gsB + (size_t)j * 8 * N_ + ko,
                  bufp + 16384 + half * 128 + j * 1024);
      }
    };

    STAGE(smem, 0);
    __syncthreads();

    const int arow = w * 16 + lr;
    const int swB = (lr & 7) << 4;
    int cur = 0;
    for (int ks = 0; ks < 16; ++ks) {
      if (ks < 15) STAGE(smem + (cur ^ 1) * 24576, ks + 1);
      const char* cb = smem + cur * 24576;
#pragma unroll
      for (int s = 0; s < 2; ++s) {
        const int m0 = s * 8 + kq * 2;
        f32x4 alo = *(const f32x4*)(cb + arow * 256 + ((m0 ^ lr) << 4));
        f32x4 ahi = *(const f32x4*)(cb + arow * 256 + (((m0 + 1) ^ lr) << 4));
        s16x8 af;
        af[0] = (short)bf16rne(alo[0]); af[1] = (short)bf16rne(alo[1]);
        af[2] = (short)bf16rne(alo[2]); af[3] = (short)bf16rne(alo[3]);
        af[4] = (short)bf16rne(ahi[0]); af[5] = (short)bf16rne(ahi[1]);
        af[6] = (short)bf16rne(ahi[2]); af[7] = (short)bf16rne(ahi[3]);
        const int ch = ((kq + 4 * s) << 4);
        s16x8 b0 = *(const s16x8*)(cb + 16384 + (0 * 16 + lr) * 128 + (ch ^ swB));
        s16x8 b1 = *(const s16x8*)(cb + 16384 + (1 * 16 + lr) * 128 + (ch ^ swB));
        s16x8 b2 = *(const s16x8*)(cb + 16384 + (2 * 16 + lr) * 128 + (ch ^ swB));
        s16x8 b3 = *(const s16x8*)(cb + 16384 + (3 * 16 + lr) * 128 + (ch ^ swB));
        acc0 = __builtin_amdgcn_mfma_f32_16x16x32_bf16(af, b0, acc0, 0, 0, 0);
        acc1 = __builtin_amdgcn_mfma_f32_16x16x32_bf16(af, b1, acc1, 0, 0, 0);
        acc2 = __builtin_amdgcn_mfma_f32_16x16x32_bf16(af, b2, acc2, 0, 0, 0);
        acc3 = __builtin_amdgcn_mfma_f32_16x16x32_bf16(af, b3, acc3, 0, 0, 0);
      }
      __syncthreads();
      cur ^= 1;
    }
  }
  // ---- epilogue: h tile into LDS ----
  {
    const float alpha = alphap[0];
    const float* dq = disq + (b << 10);
    const float* xb = x + ((size_t)b << 16);
    const int rl = w * 16 + kq * 4;
#pragma unroll
    for (int r = 0; r < 4; ++r) {
      float di = dq[i0 + rl + r];
      size_t ro = (size_t)(i0 + rl + r) * F_;
      hs[rl + r][0  + lr] = alpha * xb[ro + 0  + lr] + di * acc0[r];
      hs[rl + r][16 + lr] = alpha * xb[ro + 16 + lr] + di * acc1[r];
      hs[rl + r][32 + lr] = alpha * xb[ro + 32 + lr] + di * acc2[r];
      hs[rl + r][48 + lr] = alpha * xb[ro + 48 + lr] + di * acc3[r];
    }
#pragma unroll
    for (int it = 0; it < 4; ++it) {
      int idx = it * 1024 + t * 4;
      float4 wv = *(const float4*)&Wpre[idx];
      int p = idx >> 6, f = idx & 63;
      wft[f + 0][p] = wv.x; wft[f + 1][p] = wv.y; wft[f + 2][p] = wv.z; wft[f + 3][p] = wv.w;
    }
    __syncthreads();

    // phase 1: values tile
    const size_t base = ((size_t)(b * 16 + yb)) * 4096;
    const int cg_ = t & 15, rg = t >> 4;
    float acc[4][4] = {{0.f}};
#pragma unroll
    for (int q = 0; q < 16; ++q) {
      float4 xv0 = *(float4*)&wft[q * 4 + 0][cg_ * 4];
      float4 xv1 = *(float4*)&wft[q * 4 + 1][cg_ * 4];
      float4 xv2 = *(float4*)&wft[q * 4 + 2][cg_ * 4];
      float4 xv3 = *(float4*)&wft[q * 4 + 3][cg_ * 4];
#pragma unroll
      for (int k = 0; k < 4; ++k) {
        float4 av = *(float4*)&hs[rg * 4 + k][q * 4];
        fma_row(acc[k], av, xv0, xv1, xv2, xv3);
      }
    }
    float4 bp = *(const float4*)&bpre[cg_ * 4];
    __syncthreads();
#pragma unroll
    for (int k = 0; k < 4; ++k) {
      float4 o;
      o.x = fmaxf(acc[k][0] + bp.x, 0.f);
      o.y = fmaxf(acc[k][1] + bp.y, 0.f);
      o.z = fmaxf(acc[k][2] + bp.z, 0.f);
      o.w = fmaxf(acc[k][3] + bp.w, 0.f);
      *(float4*)&hs[rg * 4 + k][cg_ * 4] = o;
      *(float4*)&values[base + (size_t)(rg * 4 + k) * 64 + cg_ * 4] = o;
    }
#pragma unroll
    for (int it = 0; it < 8; ++it) {
      int idx = it * 1024 + t * 4;
      int ll = idx >> 6, p = idx & 63;
      float4 wv = *(const float4*)&Wfc1[idx];
      wft[p + 0][ll] = wv.x; wft[p + 1][ll] = wv.y; wft[p + 2][ll] = wv.z; wft[p + 3][ll] = wv.w;
    }
    __syncthreads();

    // phase 2: logits
    const int lg = cg_;
    float acc_a[4][4] = {{0.f}};
    float acc_b[4][4] = {{0.f}};
#pragma unroll
    for (int q = 0; q < 16; ++q) {
      float4 w0a = *(float4*)&wft[q * 4 + 0][lg * 8];
      float4 w0b = *(float4*)&wft[q * 4 + 0][lg * 8 + 4];
      float4 w1a = *(float4*)&wft[q * 4 + 1][lg * 8];
      float4 w1b = *(float4*)&wft[q * 4 + 1][lg * 8 + 4];
      float4 w2a = *(float4*)&wft[q * 4 + 2][lg * 8];
      float4 w2b = *(float4*)&wft[q * 4 + 2][lg * 8 + 4];
      float4 w3a = *(float4*)&wft[q * 4 + 3][lg * 8];
      float4 w3b = *(float4*)&wft[q * 4 + 3][lg * 8 + 4];
#pragma unroll
      for (int k = 0; k < 4; ++k) {
        float4 vv = *(float4*)&hs[rg * 4 + k][q * 4];
        fma_row(acc_a[k], vv, w0a, w1a, w2a, w3a);
        fma_row(acc_b[k], vv, w0b, w1b, w2b, w3b);
      }
    }
    float4 bfa = *(const float4*)&bfc1[lg * 8];
    float4 bfb = *(const float4*)&bfc1[lg * 8 + 4];
    float4 wka = *(const float4*)&Wkeys[lg * 8];
    float4 wkb = *(const float4*)&Wkeys[lg * 8 + 4];
#pragma unroll
    for (int k = 0; k < 4; ++k) {
      float lp = 0.f;
      lp += fmaxf(acc_a[k][0] + bfa.x, 0.f) * wka.x;
      lp += fmaxf(acc_a[k][1] + bfa.y, 0.f) * wka.y;
      lp += fmaxf(acc_a[k][2] + bfa.z, 0.f) * wka.z;
      lp += fmaxf(acc_a[k][3] + bfa.w, 0.f) * wka.w;
      lp += fmaxf(acc_b[k][0] + bfb.x, 0.f) * wkb.x;
      lp += fmaxf(acc_b[k][1] + bfb.y, 0.f) * wkb.y;
      lp += fmaxf(acc_b[k][2] + bfb.z, 0.f) * wkb.z;
      lp += fmaxf(acc_b[k][3] + bfb.w, 0.f) * wkb.w;
      part[rg * 4 + k][lg] = lp;
    }
    __syncthreads();
    if (t < 64) {
      float s = bkeysp[0];
#pragma unroll
      for (int g = 0; g < 16; ++g) s += part[t][g];
      logits[(b * 16 + yb) * 64 + t] = s;
    }
  }
  __threadfence();
  grid.sync();

  // ================= Phase TAIL (yb < 8) =================
  if (yb < 8) {
    float* sc   = (float*)(smem);
    float* red  = (float*)(smem + 4096);
    float (*pool)[64] = (float(*)[64])(smem + 4224);
    const int c = yb;
    const float isq2 = 0.70710678118654752f;
    const int base = b << 10;
    float l0 = logits[base + t] * isq2;
    float l1 = logits[base + 256 + t] * isq2;
    float l2 = logits[base + 512 + t] * isq2;
    float l3 = logits[base + 768 + t] * isq2;
    float m = fmaxf(fmaxf(l0, l1), fmaxf(l2, l3));
#pragma unroll
    for (int off = 32; off > 0; off >>= 1) m = fmaxf(m, __shfl_xor(m, off, 64));
    if (l == 0) red[w] = m;
    __syncthreads();
    m = fmaxf(fmaxf(red[0], red[1]), fmaxf(red[2], red[3]));
    float e0 = expf(l0 - m), e1 = expf(l1 - m), e2 = expf(l2 - m), e3 = expf(l3 - m);
    float s = e0 + e1 + e2 + e3;
#pragma unroll
    for (int off = 32; off > 0; off >>= 1) s += __shfl_xor(s, off, 64);
    __syncthreads();
    if (l == 0) red[w] = s;
    __syncthreads();
    s = red[0] + red[1] + red[2] + red[3];
    float inv = 1.f / s;
    sc[t]       = e0 * inv;
    sc[t + 256] = e1 * inv;
    sc[t + 512] = e2 * inv;
    sc[t + 768] = e3 * inv;
    __syncthreads();
    const int col = t & 63, g = t >> 6;
    const float* vb = values + ((size_t)b << 16);
    float acc = 0.f;
#pragma unroll
    for (int k = 0; k < 32; ++k) {
      int n = c * 128 + g + 4 * k;
      acc += sc[n] * vb[(size_t)n * 64 + col];
    }
    pool[g][col] = acc;
    __syncthreads();
    if (t < 64) vpart[(b * 8 + c) * 64 + t] = pool[0][t] + pool[1][t] + pool[2][t] + pool[3][t];
  }
  __threadfence();
  grid.sync();

  // ================= Phase OUT (block 0,0) =================
  if (b == 0 && yb == 0) {
#pragma unroll
    for (int it = 0; it < 8; ++it) {
      int bo = w * 8 + it;
      float v = 0.f;
#pragma unroll
      for (int ch = 0; ch < 8; ++ch) v += vpart[(bo * 8 + ch) * 64 + l];
      float p = v * Wout[l];
#pragma unroll
      for (int off = 32; off > 0; off >>= 1) p += __shfl_down(p, off, 64);
      if (l == 0) y[bo] = p + boutp[0];
    }
  }
}

extern "C" void kernel_launch(void* const* d_in, const int* in_sizes, int n_in,
                              void* d_out, int out_size, void* d_ws, size_t ws_size,
                              hipStream_t stream) {
  const float* x     = (const float*)d_in[0];
  const float* A     = (const float*)d_in[1];
  const float* alpha = (const float*)d_in[2];
  const float* Wpre  = (const float*)d_in[3];
  const float* bpre  = (const float*)d_in[4];
  const float* Wfc1  = (const float*)d_in[5];
  const float* bfc1  = (const float*)d_in[6];
  const float* Wkeys = (const float*)d_in[7];
  const float* bkeys = (const float*)d_in[8];
  const float* Wout  = (const float*)d_in[9];
  const float* bout  = (const float*)d_in[10];
  float* y = (float*)d_out;

  float* ws     = (float*)d_ws;
  float* disq   = ws;                   // 32768 f32
  float* values = disq + 32768;         // 2097152 f32
  float* logits = values + 2097152;     // 32768 f32
  float* vpart  = logits + 32768;       // 16384 f32
  unsigned short* xtb = (unsigned short*)(vpart + 16384);   // 2097152 bf16

  void* args[] = {
    (void*)&A, (void*)&x, (void*)&alpha,
    (void*)&Wpre, (void*)&bpre, (void*)&Wfc1, (void*)&bfc1,
    (void*)&Wkeys, (void*)&bkeys, (void*)&Wout, (void*)&bout,
    (void*)&disq, (void*)&xtb, (void*)&values, (void*)&logits,
    (void*)&vpart, (void*)&y
  };
  hipLaunchCooperativeKernel((const void*)k_mega, dim3(32, 16), dim3(256),
                             args, 0, stream);
}

// Round 13
// 135.691 us; speedup vs baseline: 3.4590x; 3.4590x over previous
//
#include <hip/hip_runtime.h>

// AttentionGCN forward. B=32, N=1024, F=64, PRE=64, L1=128. Output y[32].
//
// Pipeline (3 kernels, deterministic):
//   k_degxt    : block (jt,b) owns 16 A-rows: disq = rsqrt(rowsum), then
//                xtb[b,f,j0..j0+15] = bf16(d_j * x[b,j,f]) for those rows.
//                Also zeroes the tail counter (block 0,0).
//   k_spmm_mlp : MFMA spmm, A f32 staged via global_load_lds (pre-swizzled src,
//                linear LDS dest), cvt in-reg -> h in LDS -> values -> logits
//                (byte-identical to R10)
//   k_tailout  : softmax (redundant per chunk-block) + 128-node pool -> vpart;
//                last block (atomic counter) computes y = vpart-sum . Wout + bout

#define N_ 1024
#define F_ 64

typedef short s16x8 __attribute__((ext_vector_type(8)));
typedef float f32x4 __attribute__((ext_vector_type(4)));
typedef unsigned short u16x4 __attribute__((ext_vector_type(4)));

__device__ __forceinline__ unsigned short bf16rne(float f) {
  union { float f; unsigned u; } v; v.f = f;
  unsigned r = v.u + 0x7fffu + ((v.u >> 16) & 1u);
  return (unsigned short)(r >> 16);
}

__device__ __forceinline__ void fma_row(float (&a)[4], const float4 av,
                                        const float4 x0, const float4 x1,
                                        const float4 x2, const float4 x3) {
  a[0] += av.x * x0.x + av.y * x1.x + av.z * x2.x + av.w * x3.x;
  a[1] += av.x * x0.y + av.y * x1.y + av.z * x2.y + av.w * x3.y;
  a[2] += av.x * x0.z + av.y * x1.z + av.z * x2.z + av.w * x3.z;
  a[3] += av.x * x0.w + av.y * x1.w + av.z * x2.w + av.w * x3.w;
}

// global -> LDS direct DMA, 16B per lane; LDS dest = wave-uniform base + lane*16
__device__ __forceinline__ void stage16(const void* g, void* l) {
  auto gp = reinterpret_cast<const __attribute__((address_space(1))) void*>(
      reinterpret_cast<uintptr_t>(g));
  auto lp = reinterpret_cast<__attribute__((address_space(3))) void*>(
      reinterpret_cast<uintptr_t>(l));
  __builtin_amdgcn_global_load_lds(gp, lp, 16, 0, 0);
}

// ------- fused deg + xt: block (jt,b) owns rows j0..j0+15 -------
__global__ __launch_bounds__(256) void k_degxt(const float* __restrict__ A,
                                               const float* __restrict__ x,
                                               float* __restrict__ disq,
                                               unsigned short* __restrict__ xtb,
                                               int* __restrict__ counter) {
  __shared__ float xs[16][68];
  __shared__ float dsq[16];
  const int jt = blockIdx.x, b = blockIdx.y;
  const int j0 = jt * 16;
  const int t = threadIdx.x, w = t >> 6, l = t & 63;
  if (jt == 0 && b == 0 && t == 0) *counter = 0;   // reset tail counter each call

  // deg: wave w -> rows w*4 .. w*4+3 (same inner pattern as R10 k_deg)
  const float* Ab = A + ((size_t)b << 20) + (size_t)j0 * N_;
#pragma unroll
  for (int i = 0; i < 4; ++i) {
    const int r = w * 4 + i;
    const float4* rp = (const float4*)(Ab + (size_t)r * N_);
    float s = 0.f;
#pragma unroll
    for (int c = 0; c < 4; ++c) {
      float4 v = rp[c * 64 + l];
      s += v.x + v.y + v.z + v.w;
    }
#pragma unroll
    for (int off = 32; off > 0; off >>= 1) s += __shfl_down(s, off, 64);
    if (l == 0) {
      float d = (s != 0.f) ? s : 1.f;
      float di = rsqrtf(d);
      dsq[r] = di;
      disq[(b << 10) + j0 + r] = di;
    }
  }
  // x tile (unscaled) into LDS
  {
    int idx = t * 4, jj = idx >> 6, ff = idx & 63;
    *(float4*)&xs[jj][ff] =
        *(const float4*)&x[((size_t)b << 16) + (size_t)(j0 + jj) * F_ + ff];
  }
  __syncthreads();
  // xt: thread t -> feature f = t&63, j-quad js = (t>>6)*4
  const int f = l, js = w * 4;
  u16x4 o4;
#pragma unroll
  for (int jj = 0; jj < 4; ++jj) o4[jj] = bf16rne(xs[js + jj][f] * dsq[js + jj]);
  *(u16x4*)(xtb + (size_t)(b * 64 + f) * N_ + j0 + js) = o4;
}

// ------- fused: DMA-staged MFMA spmm (A f32 direct) -> h -> values -> logits -------
// (byte-identical to R10's k_spmm_mlp)
__global__ __launch_bounds__(256, 3) void k_spmm_mlp(const float* __restrict__ Af,
                                                     const unsigned short* __restrict__ xtb,
                                                     const float* __restrict__ x,
                                                     const float* __restrict__ disq,
                                                     const float* __restrict__ alphap,
                                                     const float* __restrict__ Wpre,
                                                     const float* __restrict__ bpre,
                                                     const float* __restrict__ Wfc1,
                                                     const float* __restrict__ bfc1,
                                                     const float* __restrict__ Wkeys,
                                                     const float* __restrict__ bkeysp,
                                                     float* __restrict__ values,
                                                     float* __restrict__ logits) {
  __shared__ __attribute__((aligned(16))) char smem[54272];
  float (*hs)[68]   = (float(*)[68])(smem);
  float (*wft)[128] = (float(*)[128])(smem + 17408);
  float (*part)[16] = (float(*)[16])(smem + 50176);

  const int t  = threadIdx.x;
  const int b  = blockIdx.x;          // batch
  const int i0 = blockIdx.y * 64;     // row block
  const int w  = t >> 6, l = t & 63;
  const int lr = l & 15, kq = l >> 4;
  const size_t bb = ((size_t)b << 20);

  const int half = (w & 1) * 32;
  const int srow4 = l >> 4;
  const int mslot = l & 15;
  const float* gA0 = Af + bb + (size_t)(i0 + half + srow4) * 1024;
  int xoff[4];
#pragma unroll
  for (int q = 0; q < 4; ++q) xoff[q] = (mslot ^ ((q * 4 + srow4) & 15)) << 2;
  const int srow8 = l >> 3;
  const int schB  = ((l & 7) ^ srow8) * 8;
  const unsigned short* gsB = xtb + (size_t)(b * 64 + half + srow8) * N_ + schB;

  auto STAGE = [&](char* bufp, int ksv) {
    if (w < 2) {
      const int ko = ksv * 64;
#pragma unroll
      for (int j = 0; j < 8; ++j)
        stage16(gA0 + (size_t)j * 4096 + xoff[j & 3] + ko,
                bufp + (half + j * 4) * 256);
    } else {
      const int ko = ksv * 64;
#pragma unroll
      for (int j = 0; j < 4; ++j)
        stage16(gsB + (size_t)j * 8 * N_ + ko,
                bufp + 16384 + half * 128 + j * 1024);
    }
  };

  STAGE(smem, 0);
  __syncthreads();

  f32x4 acc0 = {0.f, 0.f, 0.f, 0.f}, acc1 = acc0, acc2 = acc0, acc3 = acc0;
  const int arow = w * 16 + lr;
  const int swB = (lr & 7) << 4;
  int cur = 0;

  for (int ks = 0; ks < 16; ++ks) {
    if (ks < 15) STAGE(smem + (cur ^ 1) * 24576, ks + 1);
    const char* cb = smem + cur * 24576;
#pragma unroll
    for (int s = 0; s < 2; ++s) {
      const int m0 = s * 8 + kq * 2;
      f32x4 alo = *(const f32x4*)(cb + arow * 256 + ((m0 ^ lr) << 4));
      f32x4 ahi = *(const f32x4*)(cb + arow * 256 + (((m0 + 1) ^ lr) << 4));
      s16x8 af;
      af[0] = (short)bf16rne(alo[0]); af[1] = (short)bf16rne(alo[1]);
      af[2] = (short)bf16rne(alo[2]); af[3] = (short)bf16rne(alo[3]);
      af[4] = (short)bf16rne(ahi[0]); af[5] = (short)bf16rne(ahi[1]);
      af[6] = (short)bf16rne(ahi[2]); af[7] = (short)bf16rne(ahi[3]);
      const int ch = ((kq + 4 * s) << 4);
      s16x8 b0 = *(const s16x8*)(cb + 16384 + (0 * 16 + lr) * 128 + (ch ^ swB));
      s16x8 b1 = *(const s16x8*)(cb + 16384 + (1 * 16 + lr) * 128 + (ch ^ swB));
      s16x8 b2 = *(const s16x8*)(cb + 16384 + (2 * 16 + lr) * 128 + (ch ^ swB));
      s16x8 b3 = *(const s16x8*)(cb + 16384 + (3 * 16 + lr) * 128 + (ch ^ swB));
      acc0 = __builtin_amdgcn_mfma_f32_16x16x32_bf16(af, b0, acc0, 0, 0, 0);
      acc1 = __builtin_amdgcn_mfma_f32_16x16x32_bf16(af, b1, acc1, 0, 0, 0);
      acc2 = __builtin_amdgcn_mfma_f32_16x16x32_bf16(af, b2, acc2, 0, 0, 0);
      acc3 = __builtin_amdgcn_mfma_f32_16x16x32_bf16(af, b3, acc3, 0, 0, 0);
    }
    __syncthreads();
    cur ^= 1;
  }

  const float alpha = alphap[0];
  const float* dq = disq + (b << 10);
  const float* xb = x + ((size_t)b << 16);
  const int rl = w * 16 + kq * 4;
#pragma unroll
  for (int r = 0; r < 4; ++r) {
    float di = dq[i0 + rl + r];
    size_t ro = (size_t)(i0 + rl + r) * F_;
    hs[rl + r][0  + lr] = alpha * xb[ro + 0  + lr] + di * acc0[r];
    hs[rl + r][16 + lr] = alpha * xb[ro + 16 + lr] + di * acc1[r];
    hs[rl + r][32 + lr] = alpha * xb[ro + 32 + lr] + di * acc2[r];
    hs[rl + r][48 + lr] = alpha * xb[ro + 48 + lr] + di * acc3[r];
  }
#pragma unroll
  for (int it = 0; it < 4; ++it) {
    int idx = it * 1024 + t * 4;
    float4 wv = *(const float4*)&Wpre[idx];
    int p = idx >> 6, f = idx & 63;
    wft[f + 0][p] = wv.x; wft[f + 1][p] = wv.y; wft[f + 2][p] = wv.z; wft[f + 3][p] = wv.w;
  }
  __syncthreads();

  const size_t base = ((size_t)(b * 16 + blockIdx.y)) * 4096;
  const int cg = t & 15, rg = t >> 4;
  float acc[4][4] = {{0.f}};
#pragma unroll
  for (int q = 0; q < 16; ++q) {
    float4 xv0 = *(float4*)&wft[q * 4 + 0][cg * 4];
    float4 xv1 = *(float4*)&wft[q * 4 + 1][cg * 4];
    float4 xv2 = *(float4*)&wft[q * 4 + 2][cg * 4];
    float4 xv3 = *(float4*)&wft[q * 4 + 3][cg * 4];
#pragma unroll
    for (int k = 0; k < 4; ++k) {
      float4 av = *(float4*)&hs[rg * 4 + k][q * 4];
      fma_row(acc[k], av, xv0, xv1, xv2, xv3);
    }
  }
  float4 bp = *(const float4*)&bpre[cg * 4];
  __syncthreads();
#pragma unroll
  for (int k = 0; k < 4; ++k) {
    float4 o;
    o.x = fmaxf(acc[k][0] + bp.x, 0.f);
    o.y = fmaxf(acc[k][1] + bp.y, 0.f);
    o.z = fmaxf(acc[k][2] + bp.z, 0.f);
    o.w = fmaxf(acc[k][3] + bp.w, 0.f);
    *(float4*)&hs[rg * 4 + k][cg * 4] = o;
    *(float4*)&values[base + (size_t)(rg * 4 + k) * 64 + cg * 4] = o;
  }
#pragma unroll
  for (int it = 0; it < 8; ++it) {
    int idx = it * 1024 + t * 4;
    int ll = idx >> 6, p = idx & 63;
    float4 wv = *(const float4*)&Wfc1[idx];
    wft[p + 0][ll] = wv.x; wft[p + 1][ll] = wv.y; wft[p + 2][ll] = wv.z; wft[p + 3][ll] = wv.w;
  }
  __syncthreads();

  const int lg = cg;
  float acc_a[4][4] = {{0.f}};
  float acc_b[4][4] = {{0.f}};
#pragma unroll
  for (int q = 0; q < 16; ++q) {
    float4 w0a = *(float4*)&wft[q * 4 + 0][lg * 8];
    float4 w0b = *(float4*)&wft[q * 4 + 0][lg * 8 + 4];
    float4 w1a = *(float4*)&wft[q * 4 + 1][lg * 8];
    float4 w1b = *(float4*)&wft[q * 4 + 1][lg * 8 + 4];
    float4 w2a = *(float4*)&wft[q * 4 + 2][lg * 8];
    float4 w2b = *(float4*)&wft[q * 4 + 2][lg * 8 + 4];
    float4 w3a = *(float4*)&wft[q * 4 + 3][lg * 8];
    float4 w3b = *(float4*)&wft[q * 4 + 3][lg * 8 + 4];
#pragma unroll
    for (int k = 0; k < 4; ++k) {
      float4 vv = *(float4*)&hs[rg * 4 + k][q * 4];
      fma_row(acc_a[k], vv, w0a, w1a, w2a, w3a);
      fma_row(acc_b[k], vv, w0b, w1b, w2b, w3b);
    }
  }
  float4 bfa = *(const float4*)&bfc1[lg * 8];
  float4 bfb = *(const float4*)&bfc1[lg * 8 + 4];
  float4 wka = *(const float4*)&Wkeys[lg * 8];
  float4 wkb = *(const float4*)&Wkeys[lg * 8 + 4];
#pragma unroll
  for (int k = 0; k < 4; ++k) {
    float lp = 0.f;
    lp += fmaxf(acc_a[k][0] + bfa.x, 0.f) * wka.x;
    lp += fmaxf(acc_a[k][1] + bfa.y, 0.f) * wka.y;
    lp += fmaxf(acc_a[k][2] + bfa.z, 0.f) * wka.z;
    lp += fmaxf(acc_a[k][3] + bfa.w, 0.f) * wka.w;
    lp += fmaxf(acc_b[k][0] + bfb.x, 0.f) * wkb.x;
    lp += fmaxf(acc_b[k][1] + bfb.y, 0.f) * wkb.y;
    lp += fmaxf(acc_b[k][2] + bfb.z, 0.f) * wkb.z;
    lp += fmaxf(acc_b[k][3] + bfb.w, 0.f) * wkb.w;
    part[rg * 4 + k][lg] = lp;
  }
  __syncthreads();
  if (t < 64) {
    float s = bkeysp[0];
#pragma unroll
    for (int g = 0; g < 16; ++g) s += part[t][g];
    logits[(b * 16 + blockIdx.y) * 64 + t] = s;
  }
}

// ------- tail + out: softmax + pool slice -> vpart; last block -> y -------
__global__ __launch_bounds__(1024) void k_tailout(const float* __restrict__ logits,
                                                  const float* __restrict__ values,
                                                  const float* __restrict__ Wout,
                                                  const float* __restrict__ boutp,
                                                  float* __restrict__ vpart,
                                                  int* __restrict__ counter,
                                                  float* __restrict__ y) {
  const int c = blockIdx.x, b = blockIdx.y, t = threadIdx.x;
  __shared__ float sc[1024];
  __shared__ float red[16];
  __shared__ float pool[16][64];
  __shared__ int is_last;
  const float isq2 = 0.70710678118654752f;
  float lv = logits[(b << 10) + t] * isq2;
  float m = lv;
#pragma unroll
  for (int off = 32; off > 0; off >>= 1) m = fmaxf(m, __shfl_xor(m, off, 64));
  if ((t & 63) == 0) red[t >> 6] = m;
  __syncthreads();
  m = red[0];
#pragma unroll
  for (int i = 1; i < 16; ++i) m = fmaxf(m, red[i]);
  float e = expf(lv - m);
  float s = e;
#pragma unroll
  for (int off = 32; off > 0; off >>= 1) s += __shfl_xor(s, off, 64);
  __syncthreads();
  if ((t & 63) == 0) red[t >> 6] = s;
  __syncthreads();
  s = red[0];
#pragma unroll
  for (int i = 1; i < 16; ++i) s += red[i];
  sc[t] = e * (1.f / s);
  __syncthreads();
  const int col = t & 63, g = t >> 6;
  const float* vb = values + ((size_t)b << 16);
  float acc = 0.f;
#pragma unroll
  for (int k = 0; k < 8; ++k) {
    int n = c * 128 + g + 16 * k;
    acc += sc[n] * vb[(size_t)n * 64 + col];
  }
  pool[g][col] = acc;
  __syncthreads();
  if (t < 64) {
    float v = 0.f;
#pragma unroll
    for (int gg = 0; gg < 16; ++gg) v += pool[gg][t];
    vpart[(b * 8 + c) * 64 + t] = v;
  }
  // ---- last-block out ----
  __threadfence();
  if (t == 0) is_last = (atomicAdd(counter, 1) == 255);
  __syncthreads();
  if (is_last) {
    __threadfence();   // acquire: all vpart writes visible
    const int wv = t >> 6, l = t & 63;
#pragma unroll
    for (int rep = 0; rep < 2; ++rep) {
      int bo = wv * 2 + rep;
      float v = 0.f;
#pragma unroll
      for (int ch = 0; ch < 8; ++ch) v += vpart[(bo * 8 + ch) * 64 + l];
      float p = v * Wout[l];
#pragma unroll
      for (int off = 32; off > 0; off >>= 1) p += __shfl_down(p, off, 64);
      if (l == 0) y[bo] = p + boutp[0];
    }
  }
}

extern "C" void kernel_launch(void* const* d_in, const int* in_sizes, int n_in,
                              void* d_out, int out_size, void* d_ws, size_t ws_size,
                              hipStream_t stream) {
  const float* x     = (const float*)d_in[0];
  const float* A     = (const float*)d_in[1];
  const float* alpha = (const float*)d_in[2];
  const float* Wpre  = (const float*)d_in[3];
  const float* bpre  = (const float*)d_in[4];
  const float* Wfc1  = (const float*)d_in[5];
  const float* bfc1  = (const float*)d_in[6];
  const float* Wkeys = (const float*)d_in[7];
  const float* bkeys = (const float*)d_in[8];
  const float* Wout  = (const float*)d_in[9];
  const float* bout  = (const float*)d_in[10];
  float* y = (float*)d_out;

  float* ws     = (float*)d_ws;
  float* disq   = ws;                   // 32768 f32
  float* values = disq + 32768;         // 2097152 f32
  float* logits = values + 2097152;     // 32768 f32
  float* vpart  = logits + 32768;       // 16384 f32
  unsigned short* xtb = (unsigned short*)(vpart + 16384);   // 2097152 bf16
  int* counter = (int*)(xtb + 2097152);                     // 1 int

  k_degxt   <<<dim3(64, 32), dim3(256),  0, stream>>>(A, x, disq, xtb, counter);
  k_spmm_mlp<<<dim3(32, 16), dim3(256),  0, stream>>>(A, xtb, x, disq, alpha,
                                                      Wpre, bpre, Wfc1, bfc1, Wkeys, bkeys,
                                                      values, logits);
  k_tailout <<<dim3(8, 32),  dim3(1024), 0, stream>>>(logits, values, Wout, bout,
                                                      vpart, counter, y);
}

// Round 14
// 76.720 us; speedup vs baseline: 6.1177x; 1.7686x over previous
//
#include <hip/hip_runtime.h>

// AttentionGCN forward. B=32, N=1024, F=64, PRE=64, L1=128. Output y[32].
//
// Pipeline (5 kernels, deterministic, no atomics) — revert to R10 best (77.0 us):
//   k_deg      : disq[b,n] = rsqrt(rowsum(A))                 (pure 128 MB read)
//   k_xt       : xtb[b,f,j] = bf16(disq[b,j] * x[b,j,f])      (transposed B operand)
//   k_spmm_mlp : MFMA spmm; A staged f32 via global_load_lds (pre-swizzled
//                source), f32->bf16 cvt in-reg -> h in LDS -> values -> logits
//   k_tail     : softmax (redundant per chunk-block) + 128-node pool slice -> vpart
//   k_out      : y[b] = (sum_ch vpart) . Wout + bout

#define N_ 1024
#define F_ 64

typedef short s16x8 __attribute__((ext_vector_type(8)));
typedef float f32x4 __attribute__((ext_vector_type(4)));
typedef unsigned short u16x8 __attribute__((ext_vector_type(8)));

__device__ __forceinline__ unsigned short bf16rne(float f) {
  union { float f; unsigned u; } v; v.f = f;
  unsigned r = v.u + 0x7fffu + ((v.u >> 16) & 1u);
  return (unsigned short)(r >> 16);
}

__device__ __forceinline__ void fma_row(float (&a)[4], const float4 av,
                                        const float4 x0, const float4 x1,
                                        const float4 x2, const float4 x3) {
  a[0] += av.x * x0.x + av.y * x1.x + av.z * x2.x + av.w * x3.x;
  a[1] += av.x * x0.y + av.y * x1.y + av.z * x2.y + av.w * x3.y;
  a[2] += av.x * x0.z + av.y * x1.z + av.z * x2.z + av.w * x3.z;
  a[3] += av.x * x0.w + av.y * x1.w + av.z * x2.w + av.w * x3.w;
}

// global -> LDS direct DMA, 16B per lane; LDS dest = wave-uniform base + lane*16
__device__ __forceinline__ void stage16(const void* g, void* l) {
  auto gp = reinterpret_cast<const __attribute__((address_space(1))) void*>(
      reinterpret_cast<uintptr_t>(g));
  auto lp = reinterpret_cast<__attribute__((address_space(3))) void*>(
      reinterpret_cast<uintptr_t>(l));
  __builtin_amdgcn_global_load_lds(gp, lp, 16, 0, 0);
}

// ---------------- degree + d^-1/2 (pure read; warms L3 for spmm) ----------------
__global__ __launch_bounds__(256) void k_deg(const float* __restrict__ A,
                                             float* __restrict__ disq) {
  const int row  = blockIdx.x * 4 + (threadIdx.x >> 6);   // [0, B*N)
  const int lane = threadIdx.x & 63;
  const float4* a4 = (const float4*)(A + (size_t)row * N_);
  float s = 0.f;
#pragma unroll
  for (int it = 0; it < 4; ++it) {
    float4 v = a4[it * 64 + lane];
    s += v.x + v.y + v.z + v.w;
  }
#pragma unroll
  for (int off = 32; off > 0; off >>= 1) s += __shfl_down(s, off, 64);
  if (lane == 0) {
    float d = (s != 0.f) ? s : 1.f;
    disq[row] = rsqrtf(d);
  }
}

// ---------------- xtb[b][f][j] = bf16(d_j * x[b][j][f]) ----------------
__global__ __launch_bounds__(256) void k_xt(const float* __restrict__ x,
                                            const float* __restrict__ disq,
                                            unsigned short* __restrict__ xtb) {
  __shared__ float xs[64][68];
  const int b = blockIdx.y, j0 = blockIdx.x * 64, t = threadIdx.x;
  const float* xb = x + ((size_t)b << 16);
  const float* dq = disq + (b << 10);
#pragma unroll
  for (int it = 0; it < 4; ++it) {
    int idx = it * 1024 + t * 4;
    int jj = idx >> 6, ff = idx & 63;
    float4 vv = *(const float4*)&xb[(size_t)(j0 + jj) * F_ + ff];
    float sc = dq[j0 + jj];
    vv.x *= sc; vv.y *= sc; vv.z *= sc; vv.w *= sc;
    *(float4*)&xs[jj][ff] = vv;
  }
  __syncthreads();
  const int f = t & 63, ch = t >> 6;
  u16x8 o0, o1;
#pragma unroll
  for (int jj = 0; jj < 8; ++jj) o0[jj] = bf16rne(xs[ch * 16 + jj][f]);
#pragma unroll
  for (int jj = 0; jj < 8; ++jj) o1[jj] = bf16rne(xs[ch * 16 + 8 + jj][f]);
  unsigned short* dst = xtb + (size_t)(b * 64 + f) * N_ + j0 + ch * 16;
  *(u16x8*)dst = o0;
  *(u16x8*)(dst + 8) = o1;
}

// ------- fused: DMA-staged MFMA spmm (A f32 direct) -> h -> values -> logits -------
// 4 waves. Staging roles: waves 0/1 -> A rows 0-31/32-63 (f32, 256B rows,
// 16x16B slots, slot^=row&15); waves 2/3 -> B rows 0-31/32-63 (bf16, 128B rows,
// 8x16B slots, slot^=row&7). Pre-swizzled global source, linear LDS dest.
// Buffers: buf k at smem + k*24576: A [0,16384), B [16384,24576).
__global__ __launch_bounds__(256, 3) void k_spmm_mlp(const float* __restrict__ Af,
                                                     const unsigned short* __restrict__ xtb,
                                                     const float* __restrict__ x,
                                                     const float* __restrict__ disq,
                                                     const float* __restrict__ alphap,
                                                     const float* __restrict__ Wpre,
                                                     const float* __restrict__ bpre,
                                                     const float* __restrict__ Wfc1,
                                                     const float* __restrict__ bfc1,
                                                     const float* __restrict__ Wkeys,
                                                     const float* __restrict__ bkeysp,
                                                     float* __restrict__ values,
                                                     float* __restrict__ logits) {
  // Staging: [0,49152) = 2 x 24576. MLP aliases: hs f32[64][68] @0,
  // wft f32[64][128] @17408, part f32[64][16] @50176. Total 54272 -> 3 blocks/CU.
  __shared__ __attribute__((aligned(16))) char smem[54272];
  float (*hs)[68]   = (float(*)[68])(smem);
  float (*wft)[128] = (float(*)[128])(smem + 17408);
  float (*part)[16] = (float(*)[16])(smem + 50176);

  const int t  = threadIdx.x;
  const int b  = blockIdx.x;          // batch
  const int i0 = blockIdx.y * 64;     // row block
  const int w  = t >> 6, l = t & 63;
  const int lr = l & 15, kq = l >> 4;
  const size_t bb = ((size_t)b << 20);

  // ---- staging addressing ----
  const int half = (w & 1) * 32;
  // A waves (w<2): 8 instrs x (4 rows x 256B); lane covers row srow4, slot mslot.
  const int srow4 = l >> 4;           // 0..3
  const int mslot = l & 15;           // 16B slot within 256B row
  const float* gA0 = Af + bb + (size_t)(i0 + half + srow4) * 1024;
  int xoff[4];
#pragma unroll
  for (int q = 0; q < 4; ++q) xoff[q] = (mslot ^ ((q * 4 + srow4) & 15)) << 2;
  // B waves (w>=2): 4 instrs x (8 rows x 128B); lane covers row srow8, slot l&7.
  const int srow8 = l >> 3;           // 0..7
  const int schB  = ((l & 7) ^ srow8) * 8;   // pre-swizzled source chunk (shorts)
  const unsigned short* gsB = xtb + (size_t)(b * 64 + half + srow8) * N_ + schB;

  auto STAGE = [&](char* bufp, int ksv) {
    if (w < 2) {
      const int ko = ksv * 64;        // f32 k-offset
#pragma unroll
      for (int j = 0; j < 8; ++j)
        stage16(gA0 + (size_t)j * 4096 + xoff[j & 3] + ko,
                bufp + (half + j * 4) * 256);
    } else {
      const int ko = ksv * 64;        // bf16 k-offset
#pragma unroll
      for (int j = 0; j < 4; ++j)
        stage16(gsB + (size_t)j * 8 * N_ + ko,
                bufp + 16384 + half * 128 + j * 1024);
    }
  };

  // ---- prologue: DMA K-step 0 into buf0 ----
  STAGE(smem, 0);
  __syncthreads();   // implicit vmcnt(0): DMA complete

  f32x4 acc0 = {0.f, 0.f, 0.f, 0.f}, acc1 = acc0, acc2 = acc0, acc3 = acc0;
  const int arow = w * 16 + lr;       // local output row; arow&15 == lr
  const int swB = (lr & 7) << 4;      // B row-XOR for fragment reads
  int cur = 0;

  for (int ks = 0; ks < 16; ++ks) {
    if (ks < 15) STAGE(smem + (cur ^ 1) * 24576, ks + 1);  // fire-and-forget DMA
    const char* cb = smem + cur * 24576;
#pragma unroll
    for (int s = 0; s < 2; ++s) {
      // A fragment: global slots m0,m0+1 -> LDS slots (m^lr); cvt f32->bf16 RNE
      const int m0 = s * 8 + kq * 2;
      f32x4 alo = *(const f32x4*)(cb + arow * 256 + ((m0 ^ lr) << 4));
      f32x4 ahi = *(const f32x4*)(cb + arow * 256 + (((m0 + 1) ^ lr) << 4));
      s16x8 af;
      af[0] = (short)bf16rne(alo[0]); af[1] = (short)bf16rne(alo[1]);
      af[2] = (short)bf16rne(alo[2]); af[3] = (short)bf16rne(alo[3]);
      af[4] = (short)bf16rne(ahi[0]); af[5] = (short)bf16rne(ahi[1]);
      af[6] = (short)bf16rne(ahi[2]); af[7] = (short)bf16rne(ahi[3]);
      const int ch = ((kq + 4 * s) << 4);   // B chunk byte within 128B row
      s16x8 b0 = *(const s16x8*)(cb + 16384 + (0 * 16 + lr) * 128 + (ch ^ swB));
      s16x8 b1 = *(const s16x8*)(cb + 16384 + (1 * 16 + lr) * 128 + (ch ^ swB));
      s16x8 b2 = *(const s16x8*)(cb + 16384 + (2 * 16 + lr) * 128 + (ch ^ swB));
      s16x8 b3 = *(const s16x8*)(cb + 16384 + (3 * 16 + lr) * 128 + (ch ^ swB));
      acc0 = __builtin_amdgcn_mfma_f32_16x16x32_bf16(af, b0, acc0, 0, 0, 0);
      acc1 = __builtin_amdgcn_mfma_f32_16x16x32_bf16(af, b1, acc1, 0, 0, 0);
      acc2 = __builtin_amdgcn_mfma_f32_16x16x32_bf16(af, b2, acc2, 0, 0, 0);
      acc3 = __builtin_amdgcn_mfma_f32_16x16x32_bf16(af, b3, acc3, 0, 0, 0);
    }
    __syncthreads();   // drains DMA after full MFMA phase of cover
    cur ^= 1;
  }

  // ---- epilogue: h tile into LDS (staging bufs now dead) ----
  const float alpha = alphap[0];
  const float* dq = disq + (b << 10);
  const float* xb = x + ((size_t)b << 16);
  const int rl = w * 16 + kq * 4;     // local row base for C/D (col=lr, row=kq*4+r)
#pragma unroll
  for (int r = 0; r < 4; ++r) {
    float di = dq[i0 + rl + r];
    size_t ro = (size_t)(i0 + rl + r) * F_;
    hs[rl + r][0  + lr] = alpha * xb[ro + 0  + lr] + di * acc0[r];
    hs[rl + r][16 + lr] = alpha * xb[ro + 16 + lr] + di * acc1[r];
    hs[rl + r][32 + lr] = alpha * xb[ro + 32 + lr] + di * acc2[r];
    hs[rl + r][48 + lr] = alpha * xb[ro + 48 + lr] + di * acc3[r];
  }
  // load Wpre transposed into wft while hs writes settle
#pragma unroll
  for (int it = 0; it < 4; ++it) {
    int idx = it * 1024 + t * 4;
    float4 wv = *(const float4*)&Wpre[idx];
    int p = idx >> 6, f = idx & 63;
    wft[f + 0][p] = wv.x; wft[f + 1][p] = wv.y; wft[f + 2][p] = wv.z; wft[f + 3][p] = wv.w;
  }
  __syncthreads();

  // ---- phase 1: values tile ----
  const size_t base = ((size_t)(b * 16 + blockIdx.y)) * 4096;
  const int cg = t & 15, rg = t >> 4;
  float acc[4][4] = {{0.f}};
#pragma unroll
  for (int q = 0; q < 16; ++q) {
    float4 xv0 = *(float4*)&wft[q * 4 + 0][cg * 4];
    float4 xv1 = *(float4*)&wft[q * 4 + 1][cg * 4];
    float4 xv2 = *(float4*)&wft[q * 4 + 2][cg * 4];
    float4 xv3 = *(float4*)&wft[q * 4 + 3][cg * 4];
#pragma unroll
    for (int k = 0; k < 4; ++k) {
      float4 av = *(float4*)&hs[rg * 4 + k][q * 4];
      fma_row(acc[k], av, xv0, xv1, xv2, xv3);
    }
  }
  float4 bp = *(const float4*)&bpre[cg * 4];
  __syncthreads();   // phase-1 reads of hs/wft complete before overwrite
#pragma unroll
  for (int k = 0; k < 4; ++k) {
    float4 o;
    o.x = fmaxf(acc[k][0] + bp.x, 0.f);
    o.y = fmaxf(acc[k][1] + bp.y, 0.f);
    o.z = fmaxf(acc[k][2] + bp.z, 0.f);
    o.w = fmaxf(acc[k][3] + bp.w, 0.f);
    *(float4*)&hs[rg * 4 + k][cg * 4] = o;
    *(float4*)&values[base + (size_t)(rg * 4 + k) * 64 + cg * 4] = o;
  }
#pragma unroll
  for (int it = 0; it < 8; ++it) {
    int idx = it * 1024 + t * 4;
    int ll = idx >> 6, p = idx & 63;
    float4 wv = *(const float4*)&Wfc1[idx];
    wft[p + 0][ll] = wv.x; wft[p + 1][ll] = wv.y; wft[p + 2][ll] = wv.z; wft[p + 3][ll] = wv.w;
  }
  __syncthreads();

  // ---- phase 2: logits ----
  const int lg = cg;
  float acc_a[4][4] = {{0.f}};
  float acc_b[4][4] = {{0.f}};
#pragma unroll
  for (int q = 0; q < 16; ++q) {
    float4 w0a = *(float4*)&wft[q * 4 + 0][lg * 8];
    float4 w0b = *(float4*)&wft[q * 4 + 0][lg * 8 + 4];
    float4 w1a = *(float4*)&wft[q * 4 + 1][lg * 8];
    float4 w1b = *(float4*)&wft[q * 4 + 1][lg * 8 + 4];
    float4 w2a = *(float4*)&wft[q * 4 + 2][lg * 8];
    float4 w2b = *(float4*)&wft[q * 4 + 2][lg * 8 + 4];
    float4 w3a = *(float4*)&wft[q * 4 + 3][lg * 8];
    float4 w3b = *(float4*)&wft[q * 4 + 3][lg * 8 + 4];
#pragma unroll
    for (int k = 0; k < 4; ++k) {
      float4 vv = *(float4*)&hs[rg * 4 + k][q * 4];
      fma_row(acc_a[k], vv, w0a, w1a, w2a, w3a);
      fma_row(acc_b[k], vv, w0b, w1b, w2b, w3b);
    }
  }
  float4 bfa = *(const float4*)&bfc1[lg * 8];
  float4 bfb = *(const float4*)&bfc1[lg * 8 + 4];
  float4 wka = *(const float4*)&Wkeys[lg * 8];
  float4 wkb = *(const float4*)&Wkeys[lg * 8 + 4];
#pragma unroll
  for (int k = 0; k < 4; ++k) {
    float lp = 0.f;
    lp += fmaxf(acc_a[k][0] + bfa.x, 0.f) * wka.x;
    lp += fmaxf(acc_a[k][1] + bfa.y, 0.f) * wka.y;
    lp += fmaxf(acc_a[k][2] + bfa.z, 0.f) * wka.z;
    lp += fmaxf(acc_a[k][3] + bfa.w, 0.f) * wka.w;
    lp += fmaxf(acc_b[k][0] + bfb.x, 0.f) * wkb.x;
    lp += fmaxf(acc_b[k][1] + bfb.y, 0.f) * wkb.y;
    lp += fmaxf(acc_b[k][2] + bfb.z, 0.f) * wkb.z;
    lp += fmaxf(acc_b[k][3] + bfb.w, 0.f) * wkb.w;
    part[rg * 4 + k][lg] = lp;
  }
  __syncthreads();
  if (t < 64) {
    float s = bkeysp[0];
#pragma unroll
    for (int g = 0; g < 16; ++g) s += part[t][g];
    logits[(b * 16 + blockIdx.y) * 64 + t] = s;
  }
}

// ------- tail: redundant softmax per chunk-block + 128-node pool slice -------
__global__ __launch_bounds__(1024) void k_tail(const float* __restrict__ logits,
                                               const float* __restrict__ values,
                                               float* __restrict__ vpart) {
  const int c = blockIdx.x, b = blockIdx.y, t = threadIdx.x;
  __shared__ float sc[1024];
  __shared__ float red[16];
  __shared__ float pool[16][64];
  const float isq2 = 0.70710678118654752f;
  float lv = logits[(b << 10) + t] * isq2;
  float m = lv;
#pragma unroll
  for (int off = 32; off > 0; off >>= 1) m = fmaxf(m, __shfl_xor(m, off, 64));
  if ((t & 63) == 0) red[t >> 6] = m;
  __syncthreads();
  m = red[0];
#pragma unroll
  for (int i = 1; i < 16; ++i) m = fmaxf(m, red[i]);
  float e = expf(lv - m);
  float s = e;
#pragma unroll
  for (int off = 32; off > 0; off >>= 1) s += __shfl_xor(s, off, 64);
  __syncthreads();
  if ((t & 63) == 0) red[t >> 6] = s;
  __syncthreads();
  s = red[0];
#pragma unroll
  for (int i = 1; i < 16; ++i) s += red[i];
  sc[t] = e * (1.f / s);
  __syncthreads();
  const int col = t & 63, g = t >> 6;
  const float* vb = values + ((size_t)b << 16);
  float acc = 0.f;
#pragma unroll
  for (int k = 0; k < 8; ++k) {
    int n = c * 128 + g + 16 * k;
    acc += sc[n] * vb[(size_t)n * 64 + col];
  }
  pool[g][col] = acc;
  __syncthreads();
  if (t < 64) {
    float v = 0.f;
#pragma unroll
    for (int gg = 0; gg < 16; ++gg) v += pool[gg][t];
    vpart[(b * 8 + c) * 64 + t] = v;
  }
}

// ---------------- final y ----------------
__global__ __launch_bounds__(256) void k_out(const float* __restrict__ vpart,
                                             const float* __restrict__ Wout,
                                             const float* __restrict__ boutp,
                                             float* __restrict__ y) {
  const int t = threadIdx.x, w = t >> 6, lane = t & 63;
#pragma unroll
  for (int it = 0; it < 8; ++it) {
    int b = w * 8 + it;
    float v = 0.f;
#pragma unroll
    for (int ch = 0; ch < 8; ++ch) v += vpart[(b * 8 + ch) * 64 + lane];
    float p = v * Wout[lane];
#pragma unroll
    for (int off = 32; off > 0; off >>= 1) p += __shfl_down(p, off, 64);
    if (lane == 0) y[b] = p + boutp[0];
  }
}

extern "C" void kernel_launch(void* const* d_in, const int* in_sizes, int n_in,
                              void* d_out, int out_size, void* d_ws, size_t ws_size,
                              hipStream_t stream) {
  const float* x     = (const float*)d_in[0];
  const float* A     = (const float*)d_in[1];
  const float* alpha = (const float*)d_in[2];
  const float* Wpre  = (const float*)d_in[3];
  const float* bpre  = (const float*)d_in[4];
  const float* Wfc1  = (const float*)d_in[5];
  const float* bfc1  = (const float*)d_in[6];
  const float* Wkeys = (const float*)d_in[7];
  const float* bkeys = (const float*)d_in[8];
  const float* Wout  = (const float*)d_in[9];
  const float* bout  = (const float*)d_in[10];
  float* y = (float*)d_out;

  float* ws     = (float*)d_ws;
  float* disq   = ws;                   // 32768 f32
  float* values = disq + 32768;         // 2097152 f32
  float* logits = values + 2097152;     // 32768 f32
  float* vpart  = logits + 32768;       // 16384 f32
  unsigned short* xtb = (unsigned short*)(vpart + 16384);   // 2097152 bf16

  k_deg     <<<dim3(8192),   dim3(256),  0, stream>>>(A, disq);
  k_xt      <<<dim3(16, 32), dim3(256),  0, stream>>>(x, disq, xtb);
  k_spmm_mlp<<<dim3(32, 16), dim3(256),  0, stream>>>(A, xtb, x, disq, alpha,
                                                      Wpre, bpre, Wfc1, bfc1, Wkeys, bkeys,
                                                      values, logits);
  k_tail    <<<dim3(8, 32),  dim3(1024), 0, stream>>>(logits, values, vpart);
  k_out     <<<dim3(1),      dim3(256),  0, stream>>>(vpart, Wout, bout, y);
}